// Round 6
// baseline (1147.213 us; speedup 1.0000x reference)
//
#include <hip/hip_runtime.h>
#include <hip/hip_fp16.h>

// Problem constants: B=64, N=256, F_IN=768, F_OUT=256
#define NB    64
#define NN    256
#define FIN   768
#define FOUT  256

typedef _Float16 half8v __attribute__((ext_vector_type(8)));
typedef float    float4v __attribute__((ext_vector_type(4)));

__device__ inline __half2 u2h2(unsigned int u){
  union { unsigned int u; __half2 h; } cv; cv.u = u; return cv.h;
}
__device__ inline unsigned int h22u(__half2 h){
  union { __half2 h; unsigned int u; } cv; cv.h = h; return cv.u;
}

// f32 -> fp8 e4m3 (OCP, RNE) single value
__device__ inline unsigned char enc8(float v){
#if __has_builtin(__builtin_amdgcn_cvt_pk_fp8_f32)
  return (unsigned char)(__builtin_amdgcn_cvt_pk_fp8_f32(v, v, 0, false) & 0xFF);
#else
  float best = 1e30f; unsigned char bc = 0;
  for (int c = 0; c < 256; c++){
    if ((c & 0x7F) == 0x7F) continue;            // NaN codes
    int e = (c >> 3) & 15, mnt = c & 7;
    float mag = e ? ldexpf(1.f + mnt*0.125f, e-7) : ldexpf(mnt*0.125f, -6);
    float d = (c >> 7) ? -mag : mag;
    float err = fabsf(v - d);
    if (err < best){ best = err; bc = (unsigned char)c; }
  }
  return bc;
#endif
}

__device__ inline float4v mfma_fp8(long long a, long long b, float4v c){
  return __builtin_amdgcn_mfma_f32_16x16x32_fp8_fp8(a, b, c, 0, 0, 0);
}

// Swizzled fp8 weight layout for MFMA A-frags:
// off(o,k) = ((o>>4)*8 + (k>>5))*512 + ((k>>3)&3)*128 + (o&15)*8 + (k&7)

// ---------------------------------------------------------------------------
// prep: f16 conversions for the big x-side GEMMs.
// ---------------------------------------------------------------------------
__global__ __launch_bounds__(256) void prep_kernel(
    const float* __restrict__ emb_W, const float* __restrict__ ioux_W,
    const float* __restrict__ ioux_b, const float* __restrict__ coux_W,
    const float* __restrict__ coux_b,
    _Float16* __restrict__ embW16, _Float16* __restrict__ Wcat16,
    float* __restrict__ biascat)
{
  int idx = blockIdx.x*256 + threadIdx.x;
  if (idx < 196608) { embW16[idx] = (_Float16)emb_W[idx]; return; }
  idx -= 196608;
  if (idx < 196608) {
    int o = idx >> 8, k = idx & 255;
    float v = (o < 512) ? ioux_W[o*256 + k] : coux_W[(o-512)*256 + k];
    Wcat16[idx] = (_Float16)v; return;
  }
  idx -= 196608;
  if (idx < 768) { biascat[idx] = (idx < 512) ? ioux_b[idx] : coux_b[idx-512]; return; }
}

// ---------------------------------------------------------------------------
// quant: per-output-row fp8 e4m3 quantization of iouh_W / couh_W in the
// MFMA swizzled layout. invrs[o] = 1/(rowscale*16).
// ---------------------------------------------------------------------------
__global__ __launch_bounds__(256) void quant_kernel(
    const float* __restrict__ iouh_W, const float* __restrict__ couh_W,
    unsigned char* __restrict__ iouh8, unsigned char* __restrict__ couh8,
    float* __restrict__ invrs_iou, float* __restrict__ invrs_cou)
{
  const int row = blockIdx.x;       // 0..767
  const int t   = threadIdx.x;      // 0..255 (k index)
  const bool is_iou = (row < 512);
  const int rl = is_iou ? row : row - 512;
  const float w = is_iou ? iouh_W[(size_t)rl*256 + t] : couh_W[(size_t)rl*256 + t];

  __shared__ float sm[256];
  sm[t] = fabsf(w);
  __syncthreads();
  for (int s = 128; s > 0; s >>= 1){
    if (t < s) sm[t] = fmaxf(sm[t], sm[t+s]);
    __syncthreads();
  }
  const float mx = sm[0];
  const float rs = (mx > 1e-20f) ? (240.0f / mx) : 1.0f;
  const unsigned char byte = enc8(w * rs);
  const int off = ((rl>>4)*8 + (t>>5))*512 + ((t>>3)&3)*128 + (rl&15)*8 + (t&7);
  if (is_iou) iouh8[off] = byte; else couh8[off] = byte;
  if (t == 0){
    const float inv = 1.0f / (rs * 16.0f);
    if (is_iou) invrs_iou[rl] = inv; else invrs_cou[rl] = inv;
  }
}

// ---------------------------------------------------------------------------
// degmask: per (b,i): row degree inverse + transposed adjacency bitmask.
// ---------------------------------------------------------------------------
__global__ __launch_bounds__(256) void degmask_kernel(
    const float* __restrict__ adj, unsigned int* __restrict__ maskw,
    float* __restrict__ dinv)
{
  const int b = blockIdx.x, i = threadIdx.x;
  const float* ab = adj + (size_t)b*NN*NN;
  #pragma unroll
  for (int q = 0; q < 8; q++){
    unsigned int wq = 0;
    for (int jj = 0; jj < 32; jj++){
      float v = ab[(size_t)(q*32+jj)*NN + i];
      wq |= (v != 0.0f) ? (1u << jj) : 0u;
    }
    maskw[((size_t)b*NN + i)*8 + q] = wq;
  }
  float s = 0.f;
  const float4* rp = (const float4*)(ab + (size_t)i*NN);
  for (int j = 0; j < NN/4; j++){ float4 v = rp[j]; s += v.x + v.y + v.z + v.w; }
  dinv[b*NN + i] = (s != 0.f) ? 1.0f/s : 0.0f;
}

// ---------------------------------------------------------------------------
// GEMM (unchanged, validated): C = A @ Bw^T (+bias), C f16.
// ---------------------------------------------------------------------------
template<int AF32>
__global__ __launch_bounds__(256) void gemm16_kernel(
    const void* __restrict__ Aq, const _Float16* __restrict__ Bw,
    _Float16* __restrict__ Cout, const float* __restrict__ bias,
    int M, int N, int K, int ldc)
{
  const int wave = threadIdx.x >> 6;
  const int lane = threadIdx.x & 63;
  const int m0 = (blockIdx.x*4 + wave)*16;
  const int n0 = blockIdx.y*64;
  const int mrow = m0 + (lane & 15);
  const int kgrp = lane >> 4;
  float4v acc[4];
  #pragma unroll
  for (int nt = 0; nt < 4; nt++) acc[nt] = (float4v){0.f,0.f,0.f,0.f};

  for (int k0 = 0; k0 < K; k0 += 32){
    const int ka = k0 + kgrp*8;
    half8v af;
    if (AF32){
      const float* A = (const float*)Aq;
      const float4* ap = (const float4*)(A + (size_t)mrow*K + ka);
      float4 a0 = ap[0], a1 = ap[1];
      af[0]=(_Float16)a0.x; af[1]=(_Float16)a0.y; af[2]=(_Float16)a0.z; af[3]=(_Float16)a0.w;
      af[4]=(_Float16)a1.x; af[5]=(_Float16)a1.y; af[6]=(_Float16)a1.z; af[7]=(_Float16)a1.w;
    } else {
      const _Float16* A = (const _Float16*)Aq;
      af = *(const half8v*)(A + (size_t)mrow*K + ka);
    }
    #pragma unroll
    for (int nt = 0; nt < 4; nt++){
      const int ncol = n0 + nt*16 + (lane & 15);
      half8v bf = *(const half8v*)(Bw + (size_t)ncol*K + ka);
      acc[nt] = __builtin_amdgcn_mfma_f32_16x16x32_f16(af, bf, acc[nt], 0, 0, 0);
    }
  }
  #pragma unroll
  for (int nt = 0; nt < 4; nt++){
    const int ncol = n0 + nt*16 + (lane & 15);
    const float bv = bias ? bias[ncol] : 0.f;
    #pragma unroll
    for (int r = 0; r < 4; r++){
      const int orow = m0 + (lane>>4)*4 + r;
      Cout[(size_t)orow*ldc + ncol] = (_Float16)(acc[nt][r] + bv);
    }
  }
}

// ---------------------------------------------------------------------------
// scan: one block per batch element; 1024 threads = 16 waves (4/SIMD).
// R5 post-mortem: 512-thr version was multi-pipe issue-bound at 2 waves/SIMD
// (LDS ~1400cyc + L2 ~2150cyc + VALU ~1800cyc barely overlapped).
// Changes: 16 waves spread issue work; couh A-frags (16 dwords/thread at
// 1 tile/wave) are loop-invariant registers — the 64KB/step couh L2 stream
// is gone.
// LDS map (dynamic, 145920 B):
//   [0)       iouh8 swizzled   131072
//   [131072)  part (16x128 u32)  8192
//   [139264)  xp32 (256 f32)     1024
//   [140288)  xp8  (256 B)        256
//   [140544)  p8   (256 B)        256
//   [140800)  ioud (512 f32)     2048
//   [142848)  coud (256 f32)     1024
//   [143872)  z    (256 f32)     1024
//   [144896)  pm   (256 f32)     1024
// ---------------------------------------------------------------------------
#define SCAN_LDS 145920

__global__ __launch_bounds__(1024)
void scan_kernel(
    _Float16* __restrict__ Hc,          // [B*N][256] f16, init = h_e
    const _Float16* __restrict__ OUTX,  // [B*N][768] f16: [iou_x ; cou_x]
    const unsigned char* __restrict__ iouh8,  // swizzled fp8 [512][256]
    const unsigned char* __restrict__ couh8,  // swizzled fp8 [256][256]
    const float* __restrict__ invrs_iou,      // [512]
    const float* __restrict__ invrs_cou,      // [256]
    const float* __restrict__ dinv,     // [B*N]
    const unsigned int* __restrict__ maskw, // [B*N][8] (+pad)
    const float* __restrict__ iouh_b,   // [512]
    const float* __restrict__ couh_b,   // [256]
    const float* __restrict__ fc_W,     // [2][256]
    const float* __restrict__ fc_b,     // [2]
    float* __restrict__ out)            // [B][2]
{
  const int b    = blockIdx.x;
  const int t    = threadIdx.x;        // 0..1023
  const int wave = t >> 6;             // 0..15
  const int lane = t & 63;
  const int q    = lane >> 4;          // k-octet within MFMA frags
  const int r    = lane & 15;          // row within MFMA tile

  extern __shared__ __align__(16) char smem[];
  unsigned char* sh_w    = (unsigned char*)smem;
  unsigned int*  sh_part = (unsigned int*)(smem + 131072);
  float*         sh_xp32 = (float*)(smem + 139264);
  unsigned char* sh_xp8  = (unsigned char*)(smem + 140288);
  unsigned char* sh_p8   = (unsigned char*)(smem + 140544);
  float*         sh_ioud = (float*)(smem + 140800);
  float*         sh_coud = (float*)(smem + 142848);
  float*         sh_z    = (float*)(smem + 143872);
  float*         sh_pm   = (float*)(smem + 144896);

  // ---- stage iouh fp8 into LDS (once): 131072 B = 8192 uint4 ----
  {
    const uint4* src = (const uint4*)iouh8;
    uint4* dst = (uint4*)sh_w;
    #pragma unroll
    for (int qq = 0; qq < 8; qq++) dst[qq*1024 + t] = src[qq*1024 + t];
  }

  // ---- couh A-frags: loop-invariant, 16 dwords/thread (wave = tile) ----
  long long cfrag[8];
  #pragma unroll
  for (int kc = 0; kc < 8; kc++)
    cfrag[kc] = *(const long long*)(couh8 + ((size_t)(wave*8 + kc)*512) + q*128 + r*8);

  const int oc = t - 512;              // valid for t in [512,768)
  const float biou = (t < 512)            ? iouh_b[t]      : 0.f;
  const float invi = (t < 512)            ? invrs_iou[t]   : 0.f;
  const float bcou = (t >= 512 && t < 768) ? couh_b[oc]    : 0.f;
  const float invc = (t >= 512 && t < 768) ? invrs_cou[oc] : 0.f;
  float pmax = -1e30f;
  const size_t hbase = (size_t)b * (NN*FOUT);
  const _Float16* hrow0 = Hc + hbase + (size_t)(wave*16)*FOUT + lane*4;

  unsigned int mcur = maskw[((size_t)b*NN)*8 + (wave>>1)];
  __syncthreads();   // cover LDS staging

  #pragma unroll 1
  for (int i = 0; i < NN; i++){
    const size_t row = (size_t)b*NN + i;

    const unsigned int mnext = maskw[(row+1)*8 + (wave>>1)];
    const float ox = (t < 768) ? (float)OUTX[row*768 + t] : 0.f;

    // ---- aggregation: wave handles rows [16*wave, +16), mask-skip ----
    const unsigned int mw = (unsigned int)__builtin_amdgcn_readfirstlane((int)mcur);
    const unsigned int mm = (mw >> ((wave & 1)*16)) & 0xFFFFu;
    uint2 dbuf[16];
    #pragma unroll
    for (int jj = 0; jj < 16; jj++){
      if ((mm >> jj) & 1u) dbuf[jj] = *(const uint2*)(hrow0 + (size_t)jj*FOUT);
    }
    __half2 a0 = __floats2half2_rn(0.f, 0.f), a1 = a0;
    #pragma unroll
    for (int jj = 0; jj < 16; jj++){
      if ((mm >> jj) & 1u){
        a0 = __hadd2(a0, u2h2(dbuf[jj].x));
        a1 = __hadd2(a1, u2h2(dbuf[jj].y));
      }
    }
    sh_part[wave*128 + lane*2]     = h22u(a0);
    sh_part[wave*128 + lane*2 + 1] = h22u(a1);
    mcur = mnext;
    __syncthreads();                                    // B1

    // ---- reduce partials -> x_parent (f32 + fp8*16) ----
    if (t < 128){
      float s0 = 0.f, s1 = 0.f;
      #pragma unroll
      for (int w2 = 0; w2 < 16; w2++){
        __half2 p = u2h2(sh_part[w2*128 + t]);
        s0 += __low2float(p);
        s1 += __high2float(p);
      }
      const float dv = dinv[row];
      s0 *= dv; s1 *= dv;
      sh_xp32[2*t]   = s0;
      sh_xp32[2*t+1] = s1;
      const unsigned short us =
          (unsigned short)enc8(s0 * 16.f) |
          ((unsigned short)enc8(s1 * 16.f) << 8);
      ((unsigned short*)sh_xp8)[t] = us;
    }
    __syncthreads();                                    // B2

    // ---- iou matvec via fp8 MFMA: 2 tiles of 16 outputs per wave ----
    {
      float4v iacc[2];
      iacc[0] = (float4v){0.f,0.f,0.f,0.f};
      iacc[1] = iacc[0];
      #pragma unroll
      for (int kc = 0; kc < 8; kc++){
        const long long bfr = *(const long long*)(sh_xp8 + kc*32 + q*8);
        #pragma unroll
        for (int tt = 0; tt < 2; tt++){
          const long long afr = *(const long long*)(sh_w + ((size_t)((2*wave+tt)*8 + kc)*512) + q*128 + r*8);
          iacc[tt] = mfma_fp8(afr, bfr, iacc[tt]);
        }
      }
      if (r == 0){
        #pragma unroll
        for (int tt = 0; tt < 2; tt++)
          #pragma unroll
          for (int r4 = 0; r4 < 4; r4++)
            sh_ioud[(2*wave+tt)*16 + q*4 + r4] = iacc[tt][r4];
      }
    }
    __syncthreads();                                    // B3

    // ---- gates (t<512): r-gate -> p8, z-gate -> sh_z ----
    if (t < 512){
      const float iouv = sh_ioud[t]*invi + ox + biou;
      const float sg = 1.f / (1.f + __expf(-iouv));
      if (t < 256) sh_p8[t] = enc8(sg * sh_xp32[t] * 16.f);
      else         sh_z[t-256] = sg;
    }
    __syncthreads();                                    // B4

    // ---- cou matvec via fp8 MFMA: 1 tile per wave, A-frags in regs ----
    {
      float4v cacc = (float4v){0.f,0.f,0.f,0.f};
      #pragma unroll
      for (int kc = 0; kc < 8; kc++){
        const long long bfr = *(const long long*)(sh_p8 + kc*32 + q*8);
        cacc = mfma_fp8(cfrag[kc], bfr, cacc);
      }
      if (r == 0){
        #pragma unroll
        for (int r4 = 0; r4 < 4; r4++)
          sh_coud[wave*16 + q*4 + r4] = cacc[r4];
      }
    }
    __syncthreads();                                    // B5

    // ---- update (t in [512,768)) ----
    if (t >= 512 && t < 768){
      const float v   = sh_coud[oc]*invc + ox + bcou;
      const float hcv = tanhf(v);
      const float xpv = sh_xp32[oc];
      const float z   = sh_z[oc];
      const float hn  = z*xpv + (1.f - z)*hcv;
      pmax = fmaxf(pmax, hn);
      Hc[hbase + (size_t)i*FOUT + oc] = (_Float16)hn;
    }
    __syncthreads();                                    // B6
  }

  // ---- epilogue: pooled max -> fc ----
  if (t >= 512 && t < 768) sh_pm[oc] = pmax;
  __syncthreads();
  if (t < 128){
    const int c = t >> 6;   // 0 or 1
    float s = 0.f;
    #pragma unroll
    for (int qq = 0; qq < 4; qq++){
      const int f = lane + qq*64;
      s += fc_W[c*256 + f] * sh_pm[f];
    }
    #pragma unroll
    for (int off = 32; off > 0; off >>= 1) s += __shfl_xor(s, off, 64);
    if (lane == 0) out[b*2 + c] = s + fc_b[c];
  }
}

// ---------------------------------------------------------------------------
extern "C" void kernel_launch(void* const* d_in, const int* in_sizes, int n_in,
                              void* d_out, int out_size, void* d_ws, size_t ws_size,
                              hipStream_t stream)
{
  (void)in_sizes; (void)n_in; (void)out_size; (void)ws_size;
  const float* h      = (const float*)d_in[0];
  const float* adj    = (const float*)d_in[1];
  const float* emb_W  = (const float*)d_in[2];
  const float* ioux_W = (const float*)d_in[3];
  const float* ioux_b = (const float*)d_in[4];
  const float* iouh_W = (const float*)d_in[5];
  const float* iouh_b = (const float*)d_in[6];
  const float* coux_W = (const float*)d_in[7];
  const float* coux_b = (const float*)d_in[8];
  const float* couh_W = (const float*)d_in[9];
  const float* couh_b = (const float*)d_in[10];
  const float* fc_W   = (const float*)d_in[11];
  const float* fc_b   = (const float*)d_in[12];
  float* out = (float*)d_out;

  // ---- carve workspace (256B aligned chunks) ----
  size_t off = 0;
  char* base = (char*)d_ws;
  auto carve = [&](size_t bytes)->char* {
    off = (off + 255) & ~(size_t)255;
    char* p = base + off;
    off += bytes;
    return p;
  };
  _Float16* embW16 = (_Float16*)carve((size_t)256*768*2);
  _Float16* Wcat16 = (_Float16*)carve((size_t)768*256*2);
  float*    biascat= (float*)  carve((size_t)768*4);
  unsigned char* iouh8 = (unsigned char*)carve(131072);
  unsigned char* couh8 = (unsigned char*)carve(65536);
  float*    invrs_iou = (float*)carve(512*4);
  float*    invrs_cou = (float*)carve(256*4);
  float*    dinv   = (float*)  carve((size_t)NB*NN*4);
  unsigned int* maskw = (unsigned int*)carve((size_t)NB*NN*8*4 + 64); // +pad for prefetch
  _Float16* Hc     = (_Float16*)carve((size_t)NB*NN*FOUT*2);       // h_e -> h_copy
  _Float16* OUTX   = (_Float16*)carve((size_t)NB*NN*768*2);        // [iou_x ; cou_x]

  // raise dynamic LDS cap for the scan kernel (idempotent, non-stream op)
  hipFuncSetAttribute((const void*)scan_kernel,
                      hipFuncAttributeMaxDynamicSharedMemorySize, SCAN_LDS);

  // 1) f16 weight conversion for x-side GEMMs
  prep_kernel<<<dim3(1539), dim3(256), 0, stream>>>(
      emb_W, ioux_W, ioux_b, coux_W, coux_b, embW16, Wcat16, biascat);

  // 2) fp8 quantization of recurrent weights (swizzled for MFMA frags)
  quant_kernel<<<dim3(768), dim3(256), 0, stream>>>(
      iouh_W, couh_W, iouh8, couh8, invrs_iou, invrs_cou);

  // 3) degrees + adjacency column bitmasks
  degmask_kernel<<<dim3(NB), dim3(256), 0, stream>>>(adj, maskw, dinv);

  // 4) h_e = h @ emb_W^T
  gemm16_kernel<1><<<dim3(256, 4), dim3(256), 0, stream>>>(
      (const void*)h, embW16, Hc, nullptr, NB*NN, FOUT, FIN, FOUT);

  // 5) [iou_x ; cou_x] = h_e @ Wcat^T + biascat
  gemm16_kernel<0><<<dim3(256, 12), dim3(256), 0, stream>>>(
      (const void*)Hc, Wcat16, OUTX, biascat, NB*NN, 768, FOUT, 768);

  // 6) sequential tree scan (1024 threads, 16 waves)
  scan_kernel<<<dim3(NB), dim3(1024), SCAN_LDS, stream>>>(
      Hc, OUTX, iouh8, couh8, invrs_iou, invrs_cou, dinv, maskw,
      iouh_b, couh_b, fc_W, fc_b, out);
}

// Round 7
// 1042.460 us; speedup vs baseline: 1.1005x; 1.1005x over previous
//
#include <hip/hip_runtime.h>
#include <hip/hip_fp16.h>

// Problem constants: B=64, N=256, F_IN=768, F_OUT=256
#define NB    64
#define NN    256
#define FIN   768
#define FOUT  256

typedef _Float16 half8v __attribute__((ext_vector_type(8)));
typedef float    float4v __attribute__((ext_vector_type(4)));

__device__ inline __half2 u2h2(unsigned int u){
  union { unsigned int u; __half2 h; } cv; cv.u = u; return cv.h;
}
__device__ inline unsigned int h22u(__half2 h){
  union { __half2 h; unsigned int u; } cv; cv.h = h; return cv.u;
}

// f32 -> fp8 e4m3 (OCP, RNE) single value
__device__ inline unsigned char enc8(float v){
#if __has_builtin(__builtin_amdgcn_cvt_pk_fp8_f32)
  return (unsigned char)(__builtin_amdgcn_cvt_pk_fp8_f32(v, v, 0, false) & 0xFF);
#else
  float best = 1e30f; unsigned char bc = 0;
  for (int c = 0; c < 256; c++){
    if ((c & 0x7F) == 0x7F) continue;            // NaN codes
    int e = (c >> 3) & 15, mnt = c & 7;
    float mag = e ? ldexpf(1.f + mnt*0.125f, e-7) : ldexpf(mnt*0.125f, -6);
    float d = (c >> 7) ? -mag : mag;
    float err = fabsf(v - d);
    if (err < best){ best = err; bc = (unsigned char)c; }
  }
  return bc;
#endif
}

__device__ inline float4v mfma_fp8(long long a, long long b, float4v c){
  return __builtin_amdgcn_mfma_f32_16x16x32_fp8_fp8(a, b, c, 0, 0, 0);
}

// Swizzled fp8 weight layout for MFMA A-frags:
// off(o,k) = ((o>>4)*8 + (k>>5))*512 + ((k>>3)&3)*128 + (o&15)*8 + (k&7)

// ---------------------------------------------------------------------------
// prep: f16 conversions for the big x-side GEMMs.
// ---------------------------------------------------------------------------
__global__ __launch_bounds__(256) void prep_kernel(
    const float* __restrict__ emb_W, const float* __restrict__ ioux_W,
    const float* __restrict__ ioux_b, const float* __restrict__ coux_W,
    const float* __restrict__ coux_b,
    _Float16* __restrict__ embW16, _Float16* __restrict__ Wcat16,
    float* __restrict__ biascat)
{
  int idx = blockIdx.x*256 + threadIdx.x;
  if (idx < 196608) { embW16[idx] = (_Float16)emb_W[idx]; return; }
  idx -= 196608;
  if (idx < 196608) {
    int o = idx >> 8, k = idx & 255;
    float v = (o < 512) ? ioux_W[o*256 + k] : coux_W[(o-512)*256 + k];
    Wcat16[idx] = (_Float16)v; return;
  }
  idx -= 196608;
  if (idx < 768) { biascat[idx] = (idx < 512) ? ioux_b[idx] : coux_b[idx-512]; return; }
}

// ---------------------------------------------------------------------------
// quant: per-output-row fp8 e4m3 quantization of iouh_W / couh_W in the
// MFMA swizzled layout. invrs[o] = 1/(rowscale*16).
// ---------------------------------------------------------------------------
__global__ __launch_bounds__(256) void quant_kernel(
    const float* __restrict__ iouh_W, const float* __restrict__ couh_W,
    unsigned char* __restrict__ iouh8, unsigned char* __restrict__ couh8,
    float* __restrict__ invrs_iou, float* __restrict__ invrs_cou)
{
  const int row = blockIdx.x;       // 0..767
  const int t   = threadIdx.x;      // 0..255 (k index)
  const bool is_iou = (row < 512);
  const int rl = is_iou ? row : row - 512;
  const float w = is_iou ? iouh_W[(size_t)rl*256 + t] : couh_W[(size_t)rl*256 + t];

  __shared__ float sm[256];
  sm[t] = fabsf(w);
  __syncthreads();
  for (int s = 128; s > 0; s >>= 1){
    if (t < s) sm[t] = fmaxf(sm[t], sm[t+s]);
    __syncthreads();
  }
  const float mx = sm[0];
  const float rs = (mx > 1e-20f) ? (240.0f / mx) : 1.0f;
  const unsigned char byte = enc8(w * rs);
  const int off = ((rl>>4)*8 + (t>>5))*512 + ((t>>3)&3)*128 + (rl&15)*8 + (t&7);
  if (is_iou) iouh8[off] = byte; else couh8[off] = byte;
  if (t == 0){
    const float inv = 1.0f / (rs * 16.0f);
    if (is_iou) invrs_iou[rl] = inv; else invrs_cou[rl] = inv;
  }
}

// ---------------------------------------------------------------------------
// degmask: per (b,i): row degree inverse + transposed adjacency bitmask.
// ---------------------------------------------------------------------------
__global__ __launch_bounds__(256) void degmask_kernel(
    const float* __restrict__ adj, unsigned int* __restrict__ maskw,
    float* __restrict__ dinv)
{
  const int b = blockIdx.x, i = threadIdx.x;
  const float* ab = adj + (size_t)b*NN*NN;
  #pragma unroll
  for (int q = 0; q < 8; q++){
    unsigned int wq = 0;
    for (int jj = 0; jj < 32; jj++){
      float v = ab[(size_t)(q*32+jj)*NN + i];
      wq |= (v != 0.0f) ? (1u << jj) : 0u;
    }
    maskw[((size_t)b*NN + i)*8 + q] = wq;
  }
  float s = 0.f;
  const float4* rp = (const float4*)(ab + (size_t)i*NN);
  for (int j = 0; j < NN/4; j++){ float4 v = rp[j]; s += v.x + v.y + v.z + v.w; }
  dinv[b*NN + i] = (s != 0.f) ? 1.0f/s : 0.0f;
}

// ---------------------------------------------------------------------------
// GEMM (unchanged, validated): C = A @ Bw^T (+bias), C f16.
// ---------------------------------------------------------------------------
template<int AF32>
__global__ __launch_bounds__(256) void gemm16_kernel(
    const void* __restrict__ Aq, const _Float16* __restrict__ Bw,
    _Float16* __restrict__ Cout, const float* __restrict__ bias,
    int M, int N, int K, int ldc)
{
  const int wave = threadIdx.x >> 6;
  const int lane = threadIdx.x & 63;
  const int m0 = (blockIdx.x*4 + wave)*16;
  const int n0 = blockIdx.y*64;
  const int mrow = m0 + (lane & 15);
  const int kgrp = lane >> 4;
  float4v acc[4];
  #pragma unroll
  for (int nt = 0; nt < 4; nt++) acc[nt] = (float4v){0.f,0.f,0.f,0.f};

  for (int k0 = 0; k0 < K; k0 += 32){
    const int ka = k0 + kgrp*8;
    half8v af;
    if (AF32){
      const float* A = (const float*)Aq;
      const float4* ap = (const float4*)(A + (size_t)mrow*K + ka);
      float4 a0 = ap[0], a1 = ap[1];
      af[0]=(_Float16)a0.x; af[1]=(_Float16)a0.y; af[2]=(_Float16)a0.z; af[3]=(_Float16)a0.w;
      af[4]=(_Float16)a1.x; af[5]=(_Float16)a1.y; af[6]=(_Float16)a1.z; af[7]=(_Float16)a1.w;
    } else {
      const _Float16* A = (const _Float16*)Aq;
      af = *(const half8v*)(A + (size_t)mrow*K + ka);
    }
    #pragma unroll
    for (int nt = 0; nt < 4; nt++){
      const int ncol = n0 + nt*16 + (lane & 15);
      half8v bf = *(const half8v*)(Bw + (size_t)ncol*K + ka);
      acc[nt] = __builtin_amdgcn_mfma_f32_16x16x32_f16(af, bf, acc[nt], 0, 0, 0);
    }
  }
  #pragma unroll
  for (int nt = 0; nt < 4; nt++){
    const int ncol = n0 + nt*16 + (lane & 15);
    const float bv = bias ? bias[ncol] : 0.f;
    #pragma unroll
    for (int r = 0; r < 4; r++){
      const int orow = m0 + (lane>>4)*4 + r;
      Cout[(size_t)orow*ldc + ncol] = (_Float16)(acc[nt][r] + bv);
    }
  }
}

// ---------------------------------------------------------------------------
// scan: one block per batch element; 1024 threads = 16 waves (4/SIMD).
// R6 post-mortem: per-step floor (~3.5us) was the global-Hc recurrence chain
// (L2 latency + store-drain at every barrier), not issue throughput.
// This version inverts residency:
//  - Hc (h_copy) lives in LDS (128KB f16): agg=ds_read, update=ds_write.
//    No global load/store on the sequential chain. h_final never hits HBM.
//  - ALL weights live in VGPRs: iouh A-frags 32dw/thread + couh 16dw/thread
//    (48dw total; fits the 128-VGPR budget of a 1024-thread block — the
//    R1-R4 spills were at 192dw/256).
//  - update fused into the cou-MFMA phase (accumulator lanes finish h_new)
//    -> 5 LDS-only barriers per step.
// LDS map (dynamic, 145920 B):
//   [0)       Hc f16 [256][256]  131072
//   [131072)  part (16x128 u32)    8192
//   [139264)  xp32 (256 f32)       1024
//   [140288)  xp8  (256 B)          256
//   [140544)  p8   (256 B)          256
//   [140800)  ioud (512 f32)       2048
//   [142848)  z    (256 f32)       1024
//   [143872)  oxc  (256 f32)       1024
//   [144896)  pm   (256 f32)       1024
// ---------------------------------------------------------------------------
#define SCAN_LDS 145920

__global__ __launch_bounds__(1024)
void scan_kernel(
    const _Float16* __restrict__ Hc,    // [B*N][256] f16 = h_e (read once)
    const _Float16* __restrict__ OUTX,  // [B*N][768] f16: [iou_x ; cou_x]
    const unsigned char* __restrict__ iouh8,  // swizzled fp8 [512][256]
    const unsigned char* __restrict__ couh8,  // swizzled fp8 [256][256]
    const float* __restrict__ invrs_iou,      // [512]
    const float* __restrict__ invrs_cou,      // [256]
    const float* __restrict__ dinv,     // [B*N]
    const unsigned int* __restrict__ maskw, // [B*N][8] (+pad)
    const float* __restrict__ iouh_b,   // [512]
    const float* __restrict__ couh_b,   // [256]
    const float* __restrict__ fc_W,     // [2][256]
    const float* __restrict__ fc_b,     // [2]
    float* __restrict__ out)            // [B][2]
{
  const int b    = blockIdx.x;
  const int t    = threadIdx.x;        // 0..1023
  const int wave = t >> 6;             // 0..15
  const int lane = t & 63;
  const int q    = lane >> 4;          // k-octet within MFMA frags
  const int r    = lane & 15;          // row within MFMA tile

  extern __shared__ __align__(16) char smem[];
  _Float16*      sh_hc   = (_Float16*)smem;
  unsigned int*  sh_part = (unsigned int*)(smem + 131072);
  float*         sh_xp32 = (float*)(smem + 139264);
  unsigned char* sh_xp8  = (unsigned char*)(smem + 140288);
  unsigned char* sh_p8   = (unsigned char*)(smem + 140544);
  float*         sh_ioud = (float*)(smem + 140800);
  float*         sh_z    = (float*)(smem + 142848);
  float*         sh_oxc  = (float*)(smem + 143872);
  float*         sh_pm   = (float*)(smem + 144896);

  // ---- stage h_e into LDS Hc: 131072 B = 8192 uint4 ----
  {
    const uint4* src = (const uint4*)(Hc + (size_t)b*NN*FOUT);
    uint4* dst = (uint4*)sh_hc;
    #pragma unroll
    for (int k = 0; k < 8; k++) dst[k*1024 + t] = src[k*1024 + t];
  }

  // ---- weights into registers (48 dwords/thread, loop-invariant) ----
  long long ifrag[2][8];
  #pragma unroll
  for (int tt = 0; tt < 2; tt++)
    #pragma unroll
    for (int kc = 0; kc < 8; kc++)
      ifrag[tt][kc] = *(const long long*)(iouh8 + (size_t)(((2*wave+tt)*8 + kc)*512) + q*128 + r*8);
  long long cfrag[8];
  #pragma unroll
  for (int kc = 0; kc < 8; kc++)
    cfrag[kc] = *(const long long*)(couh8 + (size_t)((wave*8 + kc)*512) + q*128 + r*8);

  const int oc = t - 512;              // valid for t in [512,768)
  const float biou = (t < 512)             ? iouh_b[t]    : 0.f;
  const float invi = (t < 512)             ? invrs_iou[t] : 0.f;
  const float bcou = (t >= 512 && t < 768) ? couh_b[oc]   : 0.f;
  float invc4[4] = {0.f,0.f,0.f,0.f};
  if (r == 0){
    #pragma unroll
    for (int r4 = 0; r4 < 4; r4++) invc4[r4] = invrs_cou[wave*16 + q*4 + r4];
  }
  float pmax4[4] = {-1e30f,-1e30f,-1e30f,-1e30f};

  unsigned int mcur = maskw[((size_t)b*NN)*8 + (wave>>1)];
  __syncthreads();   // cover LDS staging

  #pragma unroll 1
  for (int i = 0; i < NN; i++){
    const size_t row = (size_t)b*NN + i;

    const unsigned int mnext = maskw[(row+1)*8 + (wave>>1)];
    const float ox = (t < 768) ? (float)OUTX[row*768 + t] : 0.f;
    const float dv = (t < 128) ? dinv[row] : 0.f;

    // ---- aggregation from LDS: wave handles rows [16*wave,+16), mask-skip
    const unsigned int mw = (unsigned int)__builtin_amdgcn_readfirstlane((int)mcur);
    const unsigned int mm = (mw >> ((wave & 1)*16)) & 0xFFFFu;
    const _Float16* hrow0 = sh_hc + (size_t)(wave*16)*FOUT + lane*4;
    __half2 a0 = __floats2half2_rn(0.f, 0.f), a1 = a0;
    #pragma unroll
    for (int ch = 0; ch < 2; ch++){
      uint2 dbuf[8];
      #pragma unroll
      for (int j2 = 0; j2 < 8; j2++){
        const int jj = ch*8 + j2;
        if ((mm >> jj) & 1u) dbuf[j2] = *(const uint2*)(hrow0 + (size_t)jj*FOUT);
      }
      #pragma unroll
      for (int j2 = 0; j2 < 8; j2++){
        const int jj = ch*8 + j2;
        if ((mm >> jj) & 1u){
          a0 = __hadd2(a0, u2h2(dbuf[j2].x));
          a1 = __hadd2(a1, u2h2(dbuf[j2].y));
        }
      }
    }
    sh_part[wave*128 + lane*2]     = h22u(a0);
    sh_part[wave*128 + lane*2 + 1] = h22u(a1);
    mcur = mnext;
    __syncthreads();                                    // B1

    // ---- reduce partials -> x_parent (f32 + fp8*16) ----
    if (t < 128){
      float s0 = 0.f, s1 = 0.f;
      #pragma unroll
      for (int w2 = 0; w2 < 16; w2++){
        __half2 p = u2h2(sh_part[w2*128 + t]);
        s0 += __low2float(p);
        s1 += __high2float(p);
      }
      s0 *= dv; s1 *= dv;
      sh_xp32[2*t]   = s0;
      sh_xp32[2*t+1] = s1;
      const unsigned short us =
          (unsigned short)enc8(s0 * 16.f) |
          ((unsigned short)enc8(s1 * 16.f) << 8);
      ((unsigned short*)sh_xp8)[t] = us;
    }
    __syncthreads();                                    // B2

    // ---- iou matvec via fp8 MFMA: 2 tiles/wave, A-frags in registers ----
    {
      float4v iacc[2];
      iacc[0] = (float4v){0.f,0.f,0.f,0.f};
      iacc[1] = iacc[0];
      #pragma unroll
      for (int kc = 0; kc < 8; kc++){
        const long long bfr = *(const long long*)(sh_xp8 + kc*32 + q*8);
        iacc[0] = mfma_fp8(ifrag[0][kc], bfr, iacc[0]);
        iacc[1] = mfma_fp8(ifrag[1][kc], bfr, iacc[1]);
      }
      if (r == 0){
        #pragma unroll
        for (int tt = 0; tt < 2; tt++)
          #pragma unroll
          for (int r4 = 0; r4 < 4; r4++)
            sh_ioud[(2*wave+tt)*16 + q*4 + r4] = iacc[tt][r4];
      }
    }
    __syncthreads();                                    // B3

    // ---- gates (t<512) ; oxc staging (t in [512,768)) ----
    if (t < 512){
      const float iouv = sh_ioud[t]*invi + ox + biou;
      const float sg = 1.f / (1.f + __expf(-iouv));
      if (t < 256) sh_p8[t] = enc8(sg * sh_xp32[t] * 16.f);
      else         sh_z[t-256] = sg;
    } else if (t < 768){
      sh_oxc[oc] = ox + bcou;
    }
    __syncthreads();                                    // B4

    // ---- cou matvec (A-frags in regs) + fused update ----
    {
      float4v cacc = (float4v){0.f,0.f,0.f,0.f};
      #pragma unroll
      for (int kc = 0; kc < 8; kc++){
        const long long bfr = *(const long long*)(sh_p8 + kc*32 + q*8);
        cacc = mfma_fp8(cfrag[kc], bfr, cacc);
      }
      if (r == 0){
        #pragma unroll
        for (int r4 = 0; r4 < 4; r4++){
          const int o = wave*16 + q*4 + r4;
          const float v   = cacc[r4]*invc4[r4] + sh_oxc[o];
          const float hcv = tanhf(v);
          const float z   = sh_z[o];
          const float xpv = sh_xp32[o];
          const float hn  = z*xpv + (1.f - z)*hcv;
          pmax4[r4] = fmaxf(pmax4[r4], hn);
          sh_hc[(size_t)i*FOUT + o] = (_Float16)hn;
        }
      }
    }
    __syncthreads();                                    // B5 (hc visible to next agg)
  }

  // ---- epilogue: pooled max -> fc ----
  if (r == 0){
    #pragma unroll
    for (int r4 = 0; r4 < 4; r4++) sh_pm[wave*16 + q*4 + r4] = pmax4[r4];
  }
  __syncthreads();
  if (t < 128){
    const int c = t >> 6;   // 0 or 1
    float s = 0.f;
    #pragma unroll
    for (int qq = 0; qq < 4; qq++){
      const int f = lane + qq*64;
      s += fc_W[c*256 + f] * sh_pm[f];
    }
    #pragma unroll
    for (int off = 32; off > 0; off >>= 1) s += __shfl_xor(s, off, 64);
    if (lane == 0) out[b*2 + c] = s + fc_b[c];
  }
}

// ---------------------------------------------------------------------------
extern "C" void kernel_launch(void* const* d_in, const int* in_sizes, int n_in,
                              void* d_out, int out_size, void* d_ws, size_t ws_size,
                              hipStream_t stream)
{
  (void)in_sizes; (void)n_in; (void)out_size; (void)ws_size;
  const float* h      = (const float*)d_in[0];
  const float* adj    = (const float*)d_in[1];
  const float* emb_W  = (const float*)d_in[2];
  const float* ioux_W = (const float*)d_in[3];
  const float* ioux_b = (const float*)d_in[4];
  const float* iouh_W = (const float*)d_in[5];
  const float* iouh_b = (const float*)d_in[6];
  const float* coux_W = (const float*)d_in[7];
  const float* coux_b = (const float*)d_in[8];
  const float* couh_W = (const float*)d_in[9];
  const float* couh_b = (const float*)d_in[10];
  const float* fc_W   = (const float*)d_in[11];
  const float* fc_b   = (const float*)d_in[12];
  float* out = (float*)d_out;

  // ---- carve workspace (256B aligned chunks) ----
  size_t off = 0;
  char* base = (char*)d_ws;
  auto carve = [&](size_t bytes)->char* {
    off = (off + 255) & ~(size_t)255;
    char* p = base + off;
    off += bytes;
    return p;
  };
  _Float16* embW16 = (_Float16*)carve((size_t)256*768*2);
  _Float16* Wcat16 = (_Float16*)carve((size_t)768*256*2);
  float*    biascat= (float*)  carve((size_t)768*4);
  unsigned char* iouh8 = (unsigned char*)carve(131072);
  unsigned char* couh8 = (unsigned char*)carve(65536);
  float*    invrs_iou = (float*)carve(512*4);
  float*    invrs_cou = (float*)carve(256*4);
  float*    dinv   = (float*)  carve((size_t)NB*NN*4);
  unsigned int* maskw = (unsigned int*)carve((size_t)NB*NN*8*4 + 64); // +pad for prefetch
  _Float16* Hc     = (_Float16*)carve((size_t)NB*NN*FOUT*2);       // h_e
  _Float16* OUTX   = (_Float16*)carve((size_t)NB*NN*768*2);        // [iou_x ; cou_x]

  // raise dynamic LDS cap for the scan kernel (idempotent, non-stream op)
  hipFuncSetAttribute((const void*)scan_kernel,
                      hipFuncAttributeMaxDynamicSharedMemorySize, SCAN_LDS);

  // 1) f16 weight conversion for x-side GEMMs
  prep_kernel<<<dim3(1539), dim3(256), 0, stream>>>(
      emb_W, ioux_W, ioux_b, coux_W, coux_b, embW16, Wcat16, biascat);

  // 2) fp8 quantization of recurrent weights (swizzled for MFMA frags)
  quant_kernel<<<dim3(768), dim3(256), 0, stream>>>(
      iouh_W, couh_W, iouh8, couh8, invrs_iou, invrs_cou);

  // 3) degrees + adjacency column bitmasks
  degmask_kernel<<<dim3(NB), dim3(256), 0, stream>>>(adj, maskw, dinv);

  // 4) h_e = h @ emb_W^T
  gemm16_kernel<1><<<dim3(256, 4), dim3(256), 0, stream>>>(
      (const void*)h, embW16, Hc, nullptr, NB*NN, FOUT, FIN, FOUT);

  // 5) [iou_x ; cou_x] = h_e @ Wcat^T + biascat
  gemm16_kernel<0><<<dim3(256, 12), dim3(256), 0, stream>>>(
      (const void*)Hc, Wcat16, OUTX, biascat, NB*NN, 768, FOUT, 768);

  // 6) sequential tree scan (1024 threads; Hc in LDS, weights in VGPRs)
  scan_kernel<<<dim3(NB), dim3(1024), SCAN_LDS, stream>>>(
      Hc, OUTX, iouh8, couh8, invrs_iou, invrs_cou, dinv, maskw,
      iouh_b, couh_b, fc_W, fc_b, out);
}

// Round 8
// 872.683 us; speedup vs baseline: 1.3146x; 1.1945x over previous
//
#include <hip/hip_runtime.h>
#include <hip/hip_fp16.h>

// Problem constants: B=64, N=256, F_IN=768, F_OUT=256
#define NB    64
#define NN    256
#define FIN   768
#define FOUT  256

typedef _Float16 half8v __attribute__((ext_vector_type(8)));
typedef float    float4v __attribute__((ext_vector_type(4)));

__device__ inline __half2 u2h2(unsigned int u){
  union { unsigned int u; __half2 h; } cv; cv.u = u; return cv.h;
}
__device__ inline unsigned int h22u(__half2 h){
  union { __half2 h; unsigned int u; } cv; cv.h = h; return cv.u;
}

// f32 -> fp8 e4m3 (OCP, RNE) single value
__device__ inline unsigned char enc8(float v){
#if __has_builtin(__builtin_amdgcn_cvt_pk_fp8_f32)
  return (unsigned char)(__builtin_amdgcn_cvt_pk_fp8_f32(v, v, 0, false) & 0xFF);
#else
  float best = 1e30f; unsigned char bc = 0;
  for (int c = 0; c < 256; c++){
    if ((c & 0x7F) == 0x7F) continue;            // NaN codes
    int e = (c >> 3) & 15, mnt = c & 7;
    float mag = e ? ldexpf(1.f + mnt*0.125f, e-7) : ldexpf(mnt*0.125f, -6);
    float d = (c >> 7) ? -mag : mag;
    float err = fabsf(v - d);
    if (err < best){ best = err; bc = (unsigned char)c; }
  }
  return bc;
#endif
}
// f32 pair -> 2 fp8 bytes packed in low u16
__device__ inline unsigned short enc8pair(float a, float b){
#if __has_builtin(__builtin_amdgcn_cvt_pk_fp8_f32)
  return (unsigned short)(__builtin_amdgcn_cvt_pk_fp8_f32(a, b, 0, false) & 0xFFFF);
#else
  return (unsigned short)enc8(a) | ((unsigned short)enc8(b) << 8);
#endif
}

__device__ inline float4v mfma_fp8(long long a, long long b, float4v c){
  return __builtin_amdgcn_mfma_f32_16x16x32_fp8_fp8(a, b, c, 0, 0, 0);
}

// Swizzled fp8 weight layout for MFMA A-frags:
// off(o,k) = ((o>>4)*8 + (k>>5))*512 + ((k>>3)&3)*128 + (o&15)*8 + (k&7)

// ---------------------------------------------------------------------------
// prep: f16 conversions for the big x-side GEMMs.
// ---------------------------------------------------------------------------
__global__ __launch_bounds__(256) void prep_kernel(
    const float* __restrict__ emb_W, const float* __restrict__ ioux_W,
    const float* __restrict__ ioux_b, const float* __restrict__ coux_W,
    const float* __restrict__ coux_b,
    _Float16* __restrict__ embW16, _Float16* __restrict__ Wcat16,
    float* __restrict__ biascat)
{
  int idx = blockIdx.x*256 + threadIdx.x;
  if (idx < 196608) { embW16[idx] = (_Float16)emb_W[idx]; return; }
  idx -= 196608;
  if (idx < 196608) {
    int o = idx >> 8, k = idx & 255;
    float v = (o < 512) ? ioux_W[o*256 + k] : coux_W[(o-512)*256 + k];
    Wcat16[idx] = (_Float16)v; return;
  }
  idx -= 196608;
  if (idx < 768) { biascat[idx] = (idx < 512) ? ioux_b[idx] : coux_b[idx-512]; return; }
}

// ---------------------------------------------------------------------------
// quant: per-output-row fp8 e4m3 quantization of iouh_W / couh_W in the
// MFMA swizzled layout. invrs[o] = 1/(rowscale*16).
// ---------------------------------------------------------------------------
__global__ __launch_bounds__(256) void quant_kernel(
    const float* __restrict__ iouh_W, const float* __restrict__ couh_W,
    unsigned char* __restrict__ iouh8, unsigned char* __restrict__ couh8,
    float* __restrict__ invrs_iou, float* __restrict__ invrs_cou)
{
  const int row = blockIdx.x;       // 0..767
  const int t   = threadIdx.x;      // 0..255 (k index)
  const bool is_iou = (row < 512);
  const int rl = is_iou ? row : row - 512;
  const float w = is_iou ? iouh_W[(size_t)rl*256 + t] : couh_W[(size_t)rl*256 + t];

  __shared__ float sm[256];
  sm[t] = fabsf(w);
  __syncthreads();
  for (int s = 128; s > 0; s >>= 1){
    if (t < s) sm[t] = fmaxf(sm[t], sm[t+s]);
    __syncthreads();
  }
  const float mx = sm[0];
  const float rs = (mx > 1e-20f) ? (240.0f / mx) : 1.0f;
  const unsigned char byte = enc8(w * rs);
  const int off = ((rl>>4)*8 + (t>>5))*512 + ((t>>3)&3)*128 + (rl&15)*8 + (t&7);
  if (is_iou) iouh8[off] = byte; else couh8[off] = byte;
  if (t == 0){
    const float inv = 1.0f / (rs * 16.0f);
    if (is_iou) invrs_iou[rl] = inv; else invrs_cou[rl] = inv;
  }
}

// ---------------------------------------------------------------------------
// degmask: per (b,i): row degree inverse + transposed adjacency bitmask.
// ---------------------------------------------------------------------------
__global__ __launch_bounds__(256) void degmask_kernel(
    const float* __restrict__ adj, unsigned int* __restrict__ maskw,
    float* __restrict__ dinv)
{
  const int b = blockIdx.x, i = threadIdx.x;
  const float* ab = adj + (size_t)b*NN*NN;
  #pragma unroll
  for (int q = 0; q < 8; q++){
    unsigned int wq = 0;
    for (int jj = 0; jj < 32; jj++){
      float v = ab[(size_t)(q*32+jj)*NN + i];
      wq |= (v != 0.0f) ? (1u << jj) : 0u;
    }
    maskw[((size_t)b*NN + i)*8 + q] = wq;
  }
  float s = 0.f;
  const float4* rp = (const float4*)(ab + (size_t)i*NN);
  for (int j = 0; j < NN/4; j++){ float4 v = rp[j]; s += v.x + v.y + v.z + v.w; }
  dinv[b*NN + i] = (s != 0.f) ? 1.0f/s : 0.0f;
}

// ---------------------------------------------------------------------------
// GEMM (unchanged, validated): C = A @ Bw^T (+bias), C f16.
// ---------------------------------------------------------------------------
template<int AF32>
__global__ __launch_bounds__(256) void gemm16_kernel(
    const void* __restrict__ Aq, const _Float16* __restrict__ Bw,
    _Float16* __restrict__ Cout, const float* __restrict__ bias,
    int M, int N, int K, int ldc)
{
  const int wave = threadIdx.x >> 6;
  const int lane = threadIdx.x & 63;
  const int m0 = (blockIdx.x*4 + wave)*16;
  const int n0 = blockIdx.y*64;
  const int mrow = m0 + (lane & 15);
  const int kgrp = lane >> 4;
  float4v acc[4];
  #pragma unroll
  for (int nt = 0; nt < 4; nt++) acc[nt] = (float4v){0.f,0.f,0.f,0.f};

  for (int k0 = 0; k0 < K; k0 += 32){
    const int ka = k0 + kgrp*8;
    half8v af;
    if (AF32){
      const float* A = (const float*)Aq;
      const float4* ap = (const float4*)(A + (size_t)mrow*K + ka);
      float4 a0 = ap[0], a1 = ap[1];
      af[0]=(_Float16)a0.x; af[1]=(_Float16)a0.y; af[2]=(_Float16)a0.z; af[3]=(_Float16)a0.w;
      af[4]=(_Float16)a1.x; af[5]=(_Float16)a1.y; af[6]=(_Float16)a1.z; af[7]=(_Float16)a1.w;
    } else {
      const _Float16* A = (const _Float16*)Aq;
      af = *(const half8v*)(A + (size_t)mrow*K + ka);
    }
    #pragma unroll
    for (int nt = 0; nt < 4; nt++){
      const int ncol = n0 + nt*16 + (lane & 15);
      half8v bf = *(const half8v*)(Bw + (size_t)ncol*K + ka);
      acc[nt] = __builtin_amdgcn_mfma_f32_16x16x32_f16(af, bf, acc[nt], 0, 0, 0);
    }
  }
  #pragma unroll
  for (int nt = 0; nt < 4; nt++){
    const int ncol = n0 + nt*16 + (lane & 15);
    const float bv = bias ? bias[ncol] : 0.f;
    #pragma unroll
    for (int r = 0; r < 4; r++){
      const int orow = m0 + (lane>>4)*4 + r;
      Cout[(size_t)orow*ldc + ncol] = (_Float16)(acc[nt][r] + bv);
    }
  }
}

// ---------------------------------------------------------------------------
// scan: one block per batch element; 1024 threads = 16 waves (4/SIMD).
// R7 post-mortem: WRITE_SIZE=2KB confirmed Hc-in-LDS worked; remaining cost
// is the serial phase chain (5 barriers + LDS round-trips + concentrated
// redundant VALU). R8 changes (numerics identical):
//  - gates fused into iou phase (B replicated across cols -> every lane holds
//    all D regs; lanes (q,r<8) take one output each, 1 sigmoid/lane).
//    Removes sh_ioud round-trip + one barrier (5 -> 4).
//  - update lane-split: lanes (q,r<4) do one tanh each (was 4 on r==0).
//  - OUTX read per-lane at its own feature (no t-mapped staging / sh_oxc).
//  - reduce widened to 4 waves via shfl_xor(1) pair-combine.
// LDS map (dynamic, 142848 B):
//   [0)       Hc f16 [256][256]  131072
//   [131072)  part (16x128 u32)    8192
//   [139264)  xp32 (256 f32)       1024
//   [140288)  xp8  (256 B)          256
//   [140544)  p8   (256 B)          256
//   [140800)  z    (256 f32)       1024
//   [141824)  pm   (256 f32)       1024
// ---------------------------------------------------------------------------
#define SCAN_LDS 142848

__global__ __launch_bounds__(1024)
void scan_kernel(
    const _Float16* __restrict__ Hc,    // [B*N][256] f16 = h_e (read once)
    const _Float16* __restrict__ OUTX,  // [B*N][768] f16: [iou_x ; cou_x]
    const unsigned char* __restrict__ iouh8,  // swizzled fp8 [512][256]
    const unsigned char* __restrict__ couh8,  // swizzled fp8 [256][256]
    const float* __restrict__ invrs_iou,      // [512]
    const float* __restrict__ invrs_cou,      // [256]
    const float* __restrict__ dinv,     // [B*N]
    const unsigned int* __restrict__ maskw, // [B*N][8] (+pad)
    const float* __restrict__ iouh_b,   // [512]
    const float* __restrict__ couh_b,   // [256]
    const float* __restrict__ fc_W,     // [2][256]
    const float* __restrict__ fc_b,     // [2]
    float* __restrict__ out)            // [B][2]
{
  const int b    = blockIdx.x;
  const int t    = threadIdx.x;        // 0..1023
  const int wave = t >> 6;             // 0..15
  const int lane = t & 63;
  const int q    = lane >> 4;          // k-octet within MFMA frags
  const int r    = lane & 15;          // row within MFMA tile

  extern __shared__ __align__(16) char smem[];
  _Float16*      sh_hc   = (_Float16*)smem;
  unsigned int*  sh_part = (unsigned int*)(smem + 131072);
  float*         sh_xp32 = (float*)(smem + 139264);
  unsigned char* sh_xp8  = (unsigned char*)(smem + 140288);
  unsigned char* sh_p8   = (unsigned char*)(smem + 140544);
  float*         sh_z    = (float*)(smem + 140800);
  float*         sh_pm   = (float*)(smem + 141824);

  // ---- stage h_e into LDS Hc: 131072 B = 8192 uint4 ----
  {
    const uint4* src = (const uint4*)(Hc + (size_t)b*NN*FOUT);
    uint4* dst = (uint4*)sh_hc;
    #pragma unroll
    for (int k = 0; k < 8; k++) dst[k*1024 + t] = src[k*1024 + t];
  }

  // ---- weights into registers (48 dwords/thread, loop-invariant) ----
  long long ifrag[2][8];
  #pragma unroll
  for (int tt = 0; tt < 2; tt++)
    #pragma unroll
    for (int kc = 0; kc < 8; kc++)
      ifrag[tt][kc] = *(const long long*)(iouh8 + (size_t)(((2*wave+tt)*8 + kc)*512) + q*128 + r*8);
  long long cfrag[8];
  #pragma unroll
  for (int kc = 0; kc < 8; kc++)
    cfrag[kc] = *(const long long*)(couh8 + (size_t)((wave*8 + kc)*512) + q*128 + r*8);

  // ---- per-lane output assignments (loop-invariant) ----
  // gate lane (r<8): o_iou = 32w + ((r>>2)&1)*16 + q*4 + (r&3), one sigmoid.
  // update lane (r<4): o_upd = 16w + q*4 + r, one tanh.
  const int o_iou = 32*wave + ((r>>2)&1)*16 + q*4 + (r&3);   // < 512 always
  const int o_upd = 16*wave + q*4 + (r&3);                   // < 256 always
  const float biou_l = iouh_b[o_iou];
  const float invi_l = invrs_iou[o_iou];
  const float bcou_l = couh_b[o_upd];
  const float invc_l = invrs_cou[o_upd];
  float pmax = -1e30f;

  unsigned int mcur = maskw[((size_t)b*NN)*8 + (wave>>1)];
  __syncthreads();   // cover LDS staging

  #pragma unroll 1
  for (int i = 0; i < NN; i++){
    const size_t row = (size_t)b*NN + i;

    const unsigned int mnext = maskw[(row+1)*8 + (wave>>1)];
    // per-lane OUTX operands (HBM; used ~1200+ cyc later — latency covered)
    const float oxi = (float)OUTX[row*768 + o_iou];
    const float oxc = (float)OUTX[row*768 + 512 + o_upd];
    const float dv  = (t < 256) ? dinv[row] : 0.f;

    // ---- aggregation from LDS: wave handles rows [16*wave,+16), mask-skip
    const unsigned int mw = (unsigned int)__builtin_amdgcn_readfirstlane((int)mcur);
    const unsigned int mm = (mw >> ((wave & 1)*16)) & 0xFFFFu;
    const _Float16* hrow0 = sh_hc + (size_t)(wave*16)*FOUT + lane*4;
    __half2 a0 = __floats2half2_rn(0.f, 0.f), a1 = a0;
    #pragma unroll
    for (int ch = 0; ch < 2; ch++){
      uint2 dbuf[8];
      #pragma unroll
      for (int j2 = 0; j2 < 8; j2++){
        const int jj = ch*8 + j2;
        if ((mm >> jj) & 1u) dbuf[j2] = *(const uint2*)(hrow0 + (size_t)jj*FOUT);
      }
      #pragma unroll
      for (int j2 = 0; j2 < 8; j2++){
        const int jj = ch*8 + j2;
        if ((mm >> jj) & 1u){
          a0 = __hadd2(a0, u2h2(dbuf[j2].x));
          a1 = __hadd2(a1, u2h2(dbuf[j2].y));
        }
      }
    }
    *(uint2*)&sh_part[wave*128 + lane*2] = make_uint2(h22u(a0), h22u(a1));
    mcur = mnext;
    __syncthreads();                                    // B1

    // ---- reduce partials -> x_parent: 4 waves, pair-split + shfl_xor ----
    if (t < 256){
      const int p = t >> 1;        // pair index 0..127 (features 2p,2p+1)
      const int h = t & 1;         // summand half
      float s0 = 0.f, s1 = 0.f;
      #pragma unroll
      for (int w2 = 0; w2 < 8; w2++){
        __half2 pp = u2h2(sh_part[(8*h + w2)*128 + p]);
        s0 += __low2float(pp);
        s1 += __high2float(pp);
      }
      s0 += __shfl_xor(s0, 1, 64);
      s1 += __shfl_xor(s1, 1, 64);
      s0 *= dv; s1 *= dv;
      if (h == 0){
        sh_xp32[2*p]   = s0;
        sh_xp32[2*p+1] = s1;
      } else {
        ((unsigned short*)sh_xp8)[p] = enc8pair(s0 * 16.f, s1 * 16.f);
      }
    }
    __syncthreads();                                    // B2

    // ---- iou matvec via fp8 MFMA (A-frags in regs) + fused gates ----
    {
      float4v iacc[2];
      iacc[0] = (float4v){0.f,0.f,0.f,0.f};
      iacc[1] = iacc[0];
      #pragma unroll
      for (int kc = 0; kc < 8; kc++){
        const long long bfr = *(const long long*)(sh_xp8 + kc*32 + q*8);
        iacc[0] = mfma_fp8(ifrag[0][kc], bfr, iacc[0]);
        iacc[1] = mfma_fp8(ifrag[1][kc], bfr, iacc[1]);
      }
      if (r < 8){
        // select this lane's output value from the replicated accumulators
        const float4v ia = (r < 4) ? iacc[0] : iacc[1];
        const int rr = r & 3;
        const float v01 = (rr == 0) ? ia[0] : ia[1];
        const float v23 = (rr == 2) ? ia[2] : ia[3];
        const float dval = (rr < 2) ? v01 : v23;
        const float iouv = dval*invi_l + oxi + biou_l;
        const float sg = 1.f / (1.f + __expf(-iouv));
        if (o_iou < 256) sh_p8[o_iou] = enc8(sg * sh_xp32[o_iou] * 16.f);
        else             sh_z[o_iou - 256] = sg;
      }
    }
    __syncthreads();                                    // B3

    // ---- cou matvec (A-frags in regs) + lane-split fused update ----
    {
      float4v cacc = (float4v){0.f,0.f,0.f,0.f};
      #pragma unroll
      for (int kc = 0; kc < 8; kc++){
        const long long bfr = *(const long long*)(sh_p8 + kc*32 + q*8);
        cacc = mfma_fp8(cfrag[kc], bfr, cacc);
      }
      if (r < 4){
        const float c01 = (r == 0) ? cacc[0] : cacc[1];
        const float c23 = (r == 2) ? cacc[2] : cacc[3];
        const float cd  = (r < 2) ? c01 : c23;
        const float v   = cd*invc_l + oxc + bcou_l;
        const float hcv = tanhf(v);
        const float z   = sh_z[o_upd];
        const float xpv = sh_xp32[o_upd];
        const float hn  = z*xpv + (1.f - z)*hcv;
        pmax = fmaxf(pmax, hn);
        sh_hc[(size_t)i*FOUT + o_upd] = (_Float16)hn;
      }
    }
    __syncthreads();                                    // B4 (hc/p8/part reuse)
  }

  // ---- epilogue: pooled max -> fc ----
  if (r < 4) sh_pm[o_upd] = pmax;
  __syncthreads();
  if (t < 128){
    const int c = t >> 6;   // 0 or 1
    float s = 0.f;
    #pragma unroll
    for (int qq = 0; qq < 4; qq++){
      const int f = (t & 63) + qq*64;
      s += fc_W[c*256 + f] * sh_pm[f];
    }
    #pragma unroll
    for (int off = 32; off > 0; off >>= 1) s += __shfl_xor(s, off, 64);
    if ((t & 63) == 0) out[b*2 + c] = s + fc_b[c];
  }
}

// ---------------------------------------------------------------------------
extern "C" void kernel_launch(void* const* d_in, const int* in_sizes, int n_in,
                              void* d_out, int out_size, void* d_ws, size_t ws_size,
                              hipStream_t stream)
{
  (void)in_sizes; (void)n_in; (void)out_size; (void)ws_size;
  const float* h      = (const float*)d_in[0];
  const float* adj    = (const float*)d_in[1];
  const float* emb_W  = (const float*)d_in[2];
  const float* ioux_W = (const float*)d_in[3];
  const float* ioux_b = (const float*)d_in[4];
  const float* iouh_W = (const float*)d_in[5];
  const float* iouh_b = (const float*)d_in[6];
  const float* coux_W = (const float*)d_in[7];
  const float* coux_b = (const float*)d_in[8];
  const float* couh_W = (const float*)d_in[9];
  const float* couh_b = (const float*)d_in[10];
  const float* fc_W   = (const float*)d_in[11];
  const float* fc_b   = (const float*)d_in[12];
  float* out = (float*)d_out;

  // ---- carve workspace (256B aligned chunks) ----
  size_t off = 0;
  char* base = (char*)d_ws;
  auto carve = [&](size_t bytes)->char* {
    off = (off + 255) & ~(size_t)255;
    char* p = base + off;
    off += bytes;
    return p;
  };
  _Float16* embW16 = (_Float16*)carve((size_t)256*768*2);
  _Float16* Wcat16 = (_Float16*)carve((size_t)768*256*2);
  float*    biascat= (float*)  carve((size_t)768*4);
  unsigned char* iouh8 = (unsigned char*)carve(131072);
  unsigned char* couh8 = (unsigned char*)carve(65536);
  float*    invrs_iou = (float*)carve(512*4);
  float*    invrs_cou = (float*)carve(256*4);
  float*    dinv   = (float*)  carve((size_t)NB*NN*4);
  unsigned int* maskw = (unsigned int*)carve((size_t)NB*NN*8*4 + 64); // +pad for prefetch
  _Float16* Hc     = (_Float16*)carve((size_t)NB*NN*FOUT*2);       // h_e
  _Float16* OUTX   = (_Float16*)carve((size_t)NB*NN*768*2);        // [iou_x ; cou_x]

  // raise dynamic LDS cap for the scan kernel (idempotent, non-stream op)
  hipFuncSetAttribute((const void*)scan_kernel,
                      hipFuncAttributeMaxDynamicSharedMemorySize, SCAN_LDS);

  // 1) f16 weight conversion for x-side GEMMs
  prep_kernel<<<dim3(1539), dim3(256), 0, stream>>>(
      emb_W, ioux_W, ioux_b, coux_W, coux_b, embW16, Wcat16, biascat);

  // 2) fp8 quantization of recurrent weights (swizzled for MFMA frags)
  quant_kernel<<<dim3(768), dim3(256), 0, stream>>>(
      iouh_W, couh_W, iouh8, couh8, invrs_iou, invrs_cou);

  // 3) degrees + adjacency column bitmasks
  degmask_kernel<<<dim3(NB), dim3(256), 0, stream>>>(adj, maskw, dinv);

  // 4) h_e = h @ emb_W^T
  gemm16_kernel<1><<<dim3(256, 4), dim3(256), 0, stream>>>(
      (const void*)h, embW16, Hc, nullptr, NB*NN, FOUT, FIN, FOUT);

  // 5) [iou_x ; cou_x] = h_e @ Wcat^T + biascat
  gemm16_kernel<0><<<dim3(256, 12), dim3(256), 0, stream>>>(
      (const void*)Hc, Wcat16, OUTX, biascat, NB*NN, 768, FOUT, 768);

  // 6) sequential tree scan (1024 threads; Hc in LDS, weights in VGPRs)
  scan_kernel<<<dim3(NB), dim3(1024), SCAN_LDS, stream>>>(
      Hc, OUTX, iouh8, couh8, invrs_iou, invrs_cou, dinv, maskw,
      iouh_b, couh_b, fc_W, fc_b, out);
}